// Round 6
// baseline (194.125 us; speedup 1.0000x reference)
//
#include <hip/hip_runtime.h>
#include <cstddef>

#define EMBED 512
#define NHEADS 8
#define HD 64
#define SEQ 2048
#define NBH 16      // B * NHEADS
#define MROWS 4096  // B * SEQ

typedef __attribute__((ext_vector_type(8))) short bf16x8;
typedef __attribute__((ext_vector_type(4))) float f32x4;

__device__ __forceinline__ unsigned short f2bf(float x) {
    union { float f; unsigned u; } v; v.f = x;
    unsigned r = v.u + 0x7fffu + ((v.u >> 16) & 1u);
    return (unsigned short)(r >> 16);
}
__device__ __forceinline__ float bf2f(unsigned short u) {
    union { unsigned u; float f; } v; v.u = ((unsigned)u) << 16;
    return v.f;
}
// packs lo -> bits[15:0], hi -> bits[31:16] (RNE)
__device__ __forceinline__ unsigned cvt_pk_bf16(float lo, float hi) {
    unsigned r;
    asm("v_cvt_pk_bf16_f32 %0, %1, %2" : "=v"(r) : "v"(lo), "v"(hi));
    return r;
}

// ---------------------------------------------------------------------------
// K0a: split x (fp32) into x_hi + x_lo (bf16 each).
// ---------------------------------------------------------------------------
__global__ __launch_bounds__(256) void cvt_x(
    const float* __restrict__ x, unsigned short* __restrict__ xh,
    unsigned short* __restrict__ xl)
{
    const int i = blockIdx.x * 256 + threadIdx.x;      // float4 index
    float4 v = ((const float4*)x)[i];
    ushort4 h, lo;
    h.x = f2bf(v.x); lo.x = f2bf(v.x - bf2f(h.x));
    h.y = f2bf(v.y); lo.y = f2bf(v.y - bf2f(h.y));
    h.z = f2bf(v.z); lo.z = f2bf(v.z - bf2f(h.z));
    h.w = f2bf(v.w); lo.w = f2bf(v.w - bf2f(h.w));
    ((ushort4*)xh)[i] = h;
    ((ushort4*)xl)[i] = lo;
}

// ---------------------------------------------------------------------------
// K0b: weight transposes to bf16.  z=0..2: Wq/Wk/Wv -> wt[z][n][k] (hi only).
// z=3: Wo hi -> wto[0];  z=4: Wo lo -> wto[1].
// ---------------------------------------------------------------------------
__global__ __launch_bounds__(256) void cvt_w(
    const float* __restrict__ Wq, const float* __restrict__ Wk,
    const float* __restrict__ Wv, const float* __restrict__ Wo,
    unsigned short* __restrict__ wt, unsigned short* __restrict__ wto)
{
    __shared__ float Ws[64][65];
    const int z = blockIdx.z;
    const float* __restrict__ W = (z == 0) ? Wq : (z == 1) ? Wk : (z == 2) ? Wv : Wo;
    const int k0 = blockIdx.x * 64, n0 = blockIdx.y * 64;
    const int t = threadIdx.x;
#pragma unroll
    for (int l = 0; l < 4; ++l) {
        const int idx = t + 256 * l;
        const int r = idx >> 4, c4 = (idx & 15) * 4;
        float4 w = *(const float4*)(W + (size_t)(k0 + r) * EMBED + n0 + c4);
        Ws[r][c4 + 0] = w.x; Ws[r][c4 + 1] = w.y;
        Ws[r][c4 + 2] = w.z; Ws[r][c4 + 3] = w.w;
    }
    __syncthreads();
    unsigned short* __restrict__ dst =
        (z < 3) ? (wt + (size_t)z * EMBED * EMBED)
                : (wto + (size_t)(z - 3) * EMBED * EMBED);
#pragma unroll
    for (int l = 0; l < 4; ++l) {
        const int idx = t + 256 * l;
        const int rn = idx >> 4, k4 = (idx & 15) * 4;
        ushort4 o;
        if (z == 4) {
            float v0 = Ws[k4 + 0][rn], v1 = Ws[k4 + 1][rn];
            float v2 = Ws[k4 + 2][rn], v3 = Ws[k4 + 3][rn];
            o.x = f2bf(v0 - bf2f(f2bf(v0)));
            o.y = f2bf(v1 - bf2f(f2bf(v1)));
            o.z = f2bf(v2 - bf2f(f2bf(v2)));
            o.w = f2bf(v3 - bf2f(f2bf(v3)));
        } else {
            o.x = f2bf(Ws[k4 + 0][rn]);
            o.y = f2bf(Ws[k4 + 1][rn]);
            o.z = f2bf(Ws[k4 + 2][rn]);
            o.w = f2bf(Ws[k4 + 3][rn]);
        }
        *(ushort4*)(dst + (size_t)(n0 + rn) * EMBED + k0 + k4) = o;
    }
}

// ---------------------------------------------------------------------------
// K1: QKV projection on MFMA.  out = (x_hi + x_lo) @ W_z + b_z, bf16 out.
// v written to vt with per-32 kv permutation: chunk kv{32a+4g+0..3} -> pos
// 32a+8g, chunk kv{32a+16+4g+0..3} -> 32a+8g+4  (so PV B-frags are 16B).
// ---------------------------------------------------------------------------
__global__ __launch_bounds__(256) void mha_qkv_mfma(
    const unsigned short* __restrict__ xh, const unsigned short* __restrict__ xl,
    const unsigned short* __restrict__ wt,
    const float* __restrict__ bq, const float* __restrict__ bk,
    const float* __restrict__ bv,
    unsigned short* __restrict__ qo, unsigned short* __restrict__ ko,
    unsigned short* __restrict__ vt)
{
    const int m0 = blockIdx.x * 64;
    const int z  = blockIdx.y >> 3;
    const int n0 = (blockIdx.y & 7) * 64;
    const float* __restrict__ bias = (z == 0) ? bq : (z == 1) ? bk : bv;

    const int t = threadIdx.x;
    const int w = t >> 6;
    const int lane = t & 63;
    const int g = lane >> 4;
    const int c = lane & 15;

    const short* ah_row = (const short*)xh + (size_t)(m0 + 16 * w + c) * EMBED + 8 * g;
    const short* al_row = (const short*)xl + (size_t)(m0 + 16 * w + c) * EMBED + 8 * g;
    const short* wz = (const short*)wt + (size_t)z * EMBED * EMBED + 8 * g;

    f32x4 acc[4];
#pragma unroll
    for (int s = 0; s < 4; ++s) acc[s] = (f32x4){0.f, 0.f, 0.f, 0.f};

#pragma unroll 4
    for (int ch = 0; ch < 16; ++ch) {
        const int k0 = ch * 32;
        const bf16x8 ah = *(const bf16x8*)(ah_row + k0);
        const bf16x8 al = *(const bf16x8*)(al_row + k0);
#pragma unroll
        for (int s = 0; s < 4; ++s) {
            const bf16x8 bs = *(const bf16x8*)(wz + (size_t)(n0 + 16 * s + c) * EMBED + k0);
            acc[s] = __builtin_amdgcn_mfma_f32_16x16x32_bf16(ah, bs, acc[s], 0, 0, 0);
            acc[s] = __builtin_amdgcn_mfma_f32_16x16x32_bf16(al, bs, acc[s], 0, 0, 0);
        }
    }

    if (z < 2) {
        unsigned short* __restrict__ out = (z == 0) ? qo : ko;
#pragma unroll
        for (int s = 0; s < 4; ++s) {
            const int n = n0 + 16 * s + c;
            const int h = n >> 6, d = n & 63;
            const float bb = bias[n];
#pragma unroll
            for (int r = 0; r < 4; ++r) {
                const int m  = m0 + 16 * w + 4 * g + r;
                const int b_ = m >> 11, sm = m & 2047;
                out[((size_t)(b_ * NHEADS + h) * SEQ + sm) * HD + d] =
                    f2bf(acc[s][r] + bb);
            }
        }
    } else {
        const int m  = m0 + 16 * w + 4 * g;     // base kv of the 4-row chunk
        const int b_ = m >> 11, sm = m & 2047;
        const int a  = sm >> 5, rem = sm & 31;
        const int pos = 32 * a + 8 * ((rem & 15) >> 2) + ((rem >> 4) << 2);
        const int h  = n0 >> 6;
#pragma unroll
        for (int s = 0; s < 4; ++s) {
            const int d = 16 * s + c;
            const float bb = bias[n0 + d];
            ushort4 o;
            o.x = f2bf(acc[s][0] + bb);
            o.y = f2bf(acc[s][1] + bb);
            o.z = f2bf(acc[s][2] + bb);
            o.w = f2bf(acc[s][3] + bb);
            *(ushort4*)(vt + ((size_t)(b_ * NHEADS + h) * HD + d) * SEQ + pos) = o;
        }
    }
}

// ---------------------------------------------------------------------------
// K2: fused flash attention, LDS-staged K/V (XOR-swizzled), double-buffered.
// Pass 1: row sums of exp2(s*scale2).  Pass 2: normalized weights + PV.
// O written as bf16 hi+lo for the MFMA out-projection.
// ---------------------------------------------------------------------------
__global__ __launch_bounds__(256) void mha_fused(
    const short* __restrict__ qb, const short* __restrict__ kb,
    const short* __restrict__ vt,
    float* __restrict__ wts,
    unsigned short* __restrict__ attn_h, unsigned short* __restrict__ attn_l)
{
    __shared__ short Ks[2][64 * 64];
    __shared__ short Vs[2][64 * 64];

    const int bh = blockIdx.y;
    const int q0 = blockIdx.x * 64;
    const int t = threadIdx.x;
    const int w = t >> 6;
    const int lane = t & 63;
    const int g = lane >> 4;
    const int c = lane & 15;
    const int q = q0 + w * 16 + c;

    const short* qrow = qb + ((size_t)bh * SEQ + q) * HD + 8 * g;
    const bf16x8 qf0 = *(const bf16x8*)(qrow);
    const bf16x8 qf1 = *(const bf16x8*)(qrow + 32);

    const int r0 = t >> 3, bl0 = t & 7;
    const int r1 = r0 + 32;
    const int ds0 = r0 * 64 + (((bl0) ^ (r0 & 7)) << 3);
    const int ds1 = r1 * 64 + (((bl0) ^ (r1 & 7)) << 3);
    const short* kgb = kb + (size_t)bh * SEQ * HD;
    const short* vgb = vt + (size_t)bh * HD * SEQ;

    int koff[4][2];
#pragma unroll
    for (int s = 0; s < 4; ++s) {
        const int rr = c + 16 * s;
        koff[s][0] = rr * 64 + (((g    ) ^ (rr & 7)) << 3);
        koff[s][1] = rr * 64 + (((g + 4) ^ (rr & 7)) << 3);
    }
    // V frag: one b128 per (sub, half): row rv=16s+c, 16B block g (lo) / 4+g (hi)
    int voff2[4][2];
#pragma unroll
    for (int s = 0; s < 4; ++s) {
        const int rv = 16 * s + c;
        voff2[s][0] = rv * 64 + (((g    ) ^ (rv & 7)) << 3);
        voff2[s][1] = rv * 64 + (((g + 4) ^ (rv & 7)) << 3);
    }

    const float scale2 = 0.125f * 1.44269504f;   // 1/sqrt(64) * log2(e)

#define QK_FROM_LDS(KB, A0, A1, A2, A3)                                         \
    __builtin_amdgcn_s_setprio(1);                                              \
    A0 = __builtin_amdgcn_mfma_f32_16x16x32_bf16(*(const bf16x8*)((KB) + koff[0][0]), qf0, A0, 0, 0, 0); \
    A0 = __builtin_amdgcn_mfma_f32_16x16x32_bf16(*(const bf16x8*)((KB) + koff[0][1]), qf1, A0, 0, 0, 0); \
    A1 = __builtin_amdgcn_mfma_f32_16x16x32_bf16(*(const bf16x8*)((KB) + koff[1][0]), qf0, A1, 0, 0, 0); \
    A1 = __builtin_amdgcn_mfma_f32_16x16x32_bf16(*(const bf16x8*)((KB) + koff[1][1]), qf1, A1, 0, 0, 0); \
    A2 = __builtin_amdgcn_mfma_f32_16x16x32_bf16(*(const bf16x8*)((KB) + koff[2][0]), qf0, A2, 0, 0, 0); \
    A2 = __builtin_amdgcn_mfma_f32_16x16x32_bf16(*(const bf16x8*)((KB) + koff[2][1]), qf1, A2, 0, 0, 0); \
    A3 = __builtin_amdgcn_mfma_f32_16x16x32_bf16(*(const bf16x8*)((KB) + koff[3][0]), qf0, A3, 0, 0, 0); \
    A3 = __builtin_amdgcn_mfma_f32_16x16x32_bf16(*(const bf16x8*)((KB) + koff[3][1]), qf1, A3, 0, 0, 0); \
    __builtin_amdgcn_s_setprio(0);

    // ---- pass 1: row sums of exp2(s*scale2) ----------------------------
    float l = 0.f;
    {
        uint4 ka  = *(const uint4*)(kgb + (size_t)t * 8);
        uint4 kc2 = *(const uint4*)(kgb + (size_t)(t + 256) * 8);
        *(uint4*)(&Ks[0][ds0]) = ka;
        *(uint4*)(&Ks[0][ds1]) = kc2;
    }
    __syncthreads();
    int cur = 0;
    for (int kt = 0; kt < 32; ++kt) {
        uint4 ka, kc2;
        if (kt < 31) {
            const short* kg = kgb + (size_t)(kt + 1) * 64 * HD;
            ka  = *(const uint4*)(kg + (size_t)t * 8);
            kc2 = *(const uint4*)(kg + (size_t)(t + 256) * 8);
        }
        f32x4 a0 = {0.f,0.f,0.f,0.f}, a1 = {0.f,0.f,0.f,0.f};
        f32x4 a2 = {0.f,0.f,0.f,0.f}, a3 = {0.f,0.f,0.f,0.f};
        const short* Kb = &Ks[cur][0];
        QK_FROM_LDS(Kb, a0, a1, a2, a3);

        float ts = 0.f;
#pragma unroll
        for (int r = 0; r < 4; ++r) {
            ts += __builtin_amdgcn_exp2f(a0[r] * scale2);
            ts += __builtin_amdgcn_exp2f(a1[r] * scale2);
            ts += __builtin_amdgcn_exp2f(a2[r] * scale2);
            ts += __builtin_amdgcn_exp2f(a3[r] * scale2);
        }
        ts += __shfl_xor(ts, 16);
        ts += __shfl_xor(ts, 32);
        l += ts;

        if (kt < 31) {
            *(uint4*)(&Ks[cur ^ 1][ds0]) = ka;
            *(uint4*)(&Ks[cur ^ 1][ds1]) = kc2;
        }
        __syncthreads();
        cur ^= 1;
    }

    const float c0 = -__builtin_amdgcn_logf(l);   // p = exp2(s*scale2 + c0)

    // ---- pass 2: weights + PV ------------------------------------------
    f32x4 o0 = {0.f,0.f,0.f,0.f}, o1 = {0.f,0.f,0.f,0.f};
    f32x4 o2 = {0.f,0.f,0.f,0.f}, o3 = {0.f,0.f,0.f,0.f};
    float* __restrict__ wrow = wts + ((size_t)bh * SEQ + q) * SEQ;

    {
        uint4 ka  = *(const uint4*)(kgb + (size_t)t * 8);
        uint4 kc2 = *(const uint4*)(kgb + (size_t)(t + 256) * 8);
        uint4 va  = *(const uint4*)(vgb + (size_t)r0 * SEQ + bl0 * 8);
        uint4 vb  = *(const uint4*)(vgb + (size_t)r1 * SEQ + bl0 * 8);
        *(uint4*)(&Ks[0][ds0]) = ka;  *(uint4*)(&Ks[0][ds1]) = kc2;
        *(uint4*)(&Vs[0][ds0]) = va;  *(uint4*)(&Vs[0][ds1]) = vb;
    }
    __syncthreads();
    cur = 0;
    for (int kt = 0; kt < 32; ++kt) {
        const int kv0 = kt * 64;
        uint4 ka, kc2, va, vb;
        if (kt < 31) {
            const short* kg = kgb + (size_t)(kt + 1) * 64 * HD;
            ka  = *(const uint4*)(kg + (size_t)t * 8);
            kc2 = *(const uint4*)(kg + (size_t)(t + 256) * 8);
            const short* vg = vgb + (kt + 1) * 64;
            va  = *(const uint4*)(vg + (size_t)r0 * SEQ + bl0 * 8);
            vb  = *(const uint4*)(vg + (size_t)r1 * SEQ + bl0 * 8);
        }

        f32x4 a0 = {0.f,0.f,0.f,0.f}, a1 = {0.f,0.f,0.f,0.f};
        f32x4 a2 = {0.f,0.f,0.f,0.f}, a3 = {0.f,0.f,0.f,0.f};
        const short* Kb = &Ks[cur][0];
        QK_FROM_LDS(Kb, a0, a1, a2, a3);

        float pn[4][4];
#pragma unroll
        for (int r = 0; r < 4; ++r) {
            pn[0][r] = __builtin_amdgcn_exp2f(fmaf(a0[r], scale2, c0));
            pn[1][r] = __builtin_amdgcn_exp2f(fmaf(a1[r], scale2, c0));
            pn[2][r] = __builtin_amdgcn_exp2f(fmaf(a2[r], scale2, c0));
            pn[3][r] = __builtin_amdgcn_exp2f(fmaf(a3[r], scale2, c0));
        }
#pragma unroll
        for (int s = 0; s < 4; ++s) {
            float4 st;
            st.x = pn[s][0]; st.y = pn[s][1]; st.z = pn[s][2]; st.w = pn[s][3];
            *(float4*)(wrow + kv0 + 16 * s + 4 * g) = st;
        }
        union { bf16x8 v; unsigned u[4]; } pf0, pf1;
        pf0.u[0] = cvt_pk_bf16(pn[0][0], pn[0][1]);
        pf0.u[1] = cvt_pk_bf16(pn[0][2], pn[0][3]);
        pf0.u[2] = cvt_pk_bf16(pn[1][0], pn[1][1]);
        pf0.u[3] = cvt_pk_bf16(pn[1][2], pn[1][3]);
        pf1.u[0] = cvt_pk_bf16(pn[2][0], pn[2][1]);
        pf1.u[1] = cvt_pk_bf16(pn[2][2], pn[2][3]);
        pf1.u[2] = cvt_pk_bf16(pn[3][0], pn[3][1]);
        pf1.u[3] = cvt_pk_bf16(pn[3][2], pn[3][3]);

        const short* Vb = &Vs[cur][0];
        __builtin_amdgcn_s_setprio(1);
#pragma unroll
        for (int sub = 0; sub < 4; ++sub) {
            const bf16x8 vf0 = *(const bf16x8*)(Vb + voff2[sub][0]);
            const bf16x8 vf1 = *(const bf16x8*)(Vb + voff2[sub][1]);
            f32x4& o = (sub == 0) ? o0 : (sub == 1) ? o1 : (sub == 2) ? o2 : o3;
            o = __builtin_amdgcn_mfma_f32_16x16x32_bf16(pf0.v, vf0, o, 0, 0, 0);
            o = __builtin_amdgcn_mfma_f32_16x16x32_bf16(pf1.v, vf1, o, 0, 0, 0);
        }
        __builtin_amdgcn_s_setprio(0);

        if (kt < 31) {
            *(uint4*)(&Ks[cur ^ 1][ds0]) = ka;  *(uint4*)(&Ks[cur ^ 1][ds1]) = kc2;
            *(uint4*)(&Vs[cur ^ 1][ds0]) = va;  *(uint4*)(&Vs[cur ^ 1][ds1]) = vb;
        }
        __syncthreads();
        cur ^= 1;
    }

    // O epilogue: row = 4g+r, col = 16*sub + c ; write bf16 hi + lo
    const size_t abase = ((size_t)bh * SEQ + q0 + 16 * w) * HD;
#pragma unroll
    for (int r = 0; r < 4; ++r) {
        const size_t ro = abase + (size_t)(4 * g + r) * HD + c;
#pragma unroll
        for (int sub = 0; sub < 4; ++sub) {
            const float ov = (sub == 0) ? o0[r] : (sub == 1) ? o1[r]
                           : (sub == 2) ? o2[r] : o3[r];
            const unsigned short h16 = f2bf(ov);
            attn_h[ro + 16 * sub] = h16;
            attn_l[ro + 16 * sub] = f2bf(ov - bf2f(h16));
        }
    }
#undef QK_FROM_LDS
}

// ---------------------------------------------------------------------------
// K3: out = concat(attn) @ Wo + bo on MFMA (3-term split-bf16).
// Block: 32m x 64n, 4 waves (wm = w&1, wn = w>>1).  grid (128, 8).
// ---------------------------------------------------------------------------
__global__ __launch_bounds__(256) void mha_oproj_mfma(
    const unsigned short* __restrict__ ah_, const unsigned short* __restrict__ al_,
    const unsigned short* __restrict__ wto,
    const float* __restrict__ bo, float* __restrict__ out)
{
    const int m0 = blockIdx.x * 32;
    const int n0 = blockIdx.y * 64;
    const int t = threadIdx.x;
    const int w = t >> 6;
    const int lane = t & 63;
    const int g = lane >> 4;
    const int c = lane & 15;
    const int wm = w & 1, wn = w >> 1;

    const int mrow = m0 + 16 * wm + c;
    const int b_ = mrow >> 11, sm = mrow & 2047;
    const short* ahb = (const short*)ah_ + ((size_t)(b_ * NHEADS) * SEQ + sm) * HD + 8 * g;
    const short* alb = (const short*)al_ + ((size_t)(b_ * NHEADS) * SEQ + sm) * HD + 8 * g;
    const short* wh = (const short*)wto + 8 * g;
    const short* wl = wh + (size_t)EMBED * EMBED;

    f32x4 acc[2];
    acc[0] = (f32x4){0.f, 0.f, 0.f, 0.f};
    acc[1] = (f32x4){0.f, 0.f, 0.f, 0.f};

#pragma unroll 4
    for (int ch = 0; ch < 16; ++ch) {
        const size_t aoff = (size_t)(ch >> 1) * SEQ * HD + (ch & 1) * 32;
        const bf16x8 a_h = *(const bf16x8*)(ahb + aoff);
        const bf16x8 a_l = *(const bf16x8*)(alb + aoff);
#pragma unroll
        for (int s = 0; s < 2; ++s) {
            const int n = n0 + 32 * wn + 16 * s + c;
            const size_t woff = (size_t)n * EMBED + 32 * ch;
            const bf16x8 b_h = *(const bf16x8*)(wh + woff);
            const bf16x8 b_l = *(const bf16x8*)(wl + woff);
            acc[s] = __builtin_amdgcn_mfma_f32_16x16x32_bf16(a_h, b_h, acc[s], 0, 0, 0);
            acc[s] = __builtin_amdgcn_mfma_f32_16x16x32_bf16(a_l, b_h, acc[s], 0, 0, 0);
            acc[s] = __builtin_amdgcn_mfma_f32_16x16x32_bf16(a_h, b_l, acc[s], 0, 0, 0);
        }
    }

#pragma unroll
    for (int s = 0; s < 2; ++s) {
        const int n = n0 + 32 * wn + 16 * s + c;
        const float bb = bo[n];
#pragma unroll
        for (int r = 0; r < 4; ++r) {
            const int m = m0 + 16 * wm + 4 * g + r;
            out[(size_t)m * EMBED + n] = acc[s][r] + bb;
        }
    }
}

// ---------------------------------------------------------------------------
extern "C" void kernel_launch(void* const* d_in, const int* in_sizes, int n_in,
                              void* d_out, int out_size, void* d_ws, size_t ws_size,
                              hipStream_t stream)
{
    const float* x  = (const float*)d_in[0];
    const float* Wq = (const float*)d_in[1];
    const float* bq = (const float*)d_in[2];
    const float* Wk = (const float*)d_in[3];
    const float* bk = (const float*)d_in[4];
    const float* Wv = (const float*)d_in[5];
    const float* bv = (const float*)d_in[6];
    const float* Wo = (const float*)d_in[7];
    const float* bo = (const float*)d_in[8];

    float* out = (float*)d_out;                      // [2,2048,512]
    float* wts = out + (size_t)2 * SEQ * EMBED;      // [2,8,2048,2048]

    unsigned short* qbw = (unsigned short*)d_ws;             // bf16 [16][2048][64]
    unsigned short* kbw = qbw + (size_t)NBH * SEQ * HD;      // bf16 [16][2048][64]
    unsigned short* vtw = kbw + (size_t)NBH * SEQ * HD;      // bf16 [16][64][2048] (kv-permuted)
    unsigned short* ath = vtw + (size_t)NBH * SEQ * HD;      // bf16 [16][2048][64]
    unsigned short* atl = ath + (size_t)NBH * SEQ * HD;      // bf16 [16][2048][64]
    unsigned short* xh  = atl + (size_t)NBH * SEQ * HD;      // bf16 [4096][512]
    unsigned short* xl  = xh + (size_t)MROWS * EMBED;        // bf16 [4096][512]
    unsigned short* wtw = xl + (size_t)MROWS * EMBED;        // bf16 [3][512][512]
    unsigned short* wto = wtw + (size_t)3 * EMBED * EMBED;   // bf16 [2][512][512]

    cvt_x<<<dim3(MROWS * EMBED / 4 / 256), 256, 0, stream>>>(x, xh, xl);
    cvt_w<<<dim3(8, 8, 5), 256, 0, stream>>>(Wq, Wk, Wv, Wo, wtw, wto);
    mha_qkv_mfma<<<dim3(64, 24), 256, 0, stream>>>(xh, xl, wtw, bq, bk, bv,
                                                   qbw, kbw, vtw);
    mha_fused  <<<dim3(32, NBH), 256, 0, stream>>>((const short*)qbw, (const short*)kbw,
                                                   (const short*)vtw, wts, ath, atl);
    mha_oproj_mfma<<<dim3(128, 8), 256, 0, stream>>>(ath, atl, wto, bo, out);
}